// Round 14
// baseline (208.691 us; speedup 1.0000x reference)
//
#include <hip/hip_runtime.h>
#include <hip/hip_bf16.h>

// MultiHeadAttention fused pipeline, bf16 MFMA path.
// B=4 H=16 S=1024 D=64 E=1024, causal, dropout=identity.
// ws layout (48 MB):
//   [0,8M)    xb   : x as bf16            [4096][1024]
//   [8M,16M)  Wt   : W^T bf16, slots q,k,v,o each [1024][1024]
//   [16M,24M) Qb   : [4][16][1024][64] bf16
//   [24M,32M) Kb   : [4][16][1024][64] bf16
//   [32M,40M) Vt   : [4][16][64][1024] bf16  (transposed for PV B-frag)
//   [40M,48M) Ao   : attn out bf16 [4096][1024]

typedef short bf16x8 __attribute__((ext_vector_type(8)));
typedef float f32x4  __attribute__((ext_vector_type(4)));
typedef unsigned short u16;

#define MFMA_BF16(a,b,c) __builtin_amdgcn_mfma_f32_16x16x32_bf16((a),(b),(c),0,0,0)

#define ASYNC16(gp, lp) __builtin_amdgcn_global_load_lds( \
    (const __attribute__((address_space(1))) void*)(gp),  \
    (__attribute__((address_space(3))) void*)(lp), 16, 0, 0)

// Counted-vmcnt pipeline primitives (T4): raw barrier, no vmcnt(0) drain
// in steady state. sched_barrier(0) pins LDS reads after the barrier.
#define VMCNT4  asm volatile("s_waitcnt vmcnt(4)" ::: "memory")
#define VMCNT0  asm volatile("s_waitcnt vmcnt(0)" ::: "memory")
#define BARRIER __builtin_amdgcn_s_barrier()
#define SCHEDB  __builtin_amdgcn_sched_barrier(0)

__device__ __forceinline__ u16 f2bf(float f){
  unsigned int u = __float_as_uint(f);
  u += 0x7FFFu + ((u >> 16) & 1u);   // RNE
  return (u16)(u >> 16);
}

// ---------------- prep: x->bf16 (z=4) + W->W^T bf16 (z=0..3) ----------------
__global__ __launch_bounds__(256) void prep_kernel(const float* __restrict__ x,
                                                   const float* __restrict__ W0,
                                                   const float* __restrict__ W1,
                                                   const float* __restrict__ W2,
                                                   const float* __restrict__ W3,
                                                   u16* __restrict__ xb,
                                                   u16* __restrict__ Wt){
  __shared__ float t[32][33];
  const int z = blockIdx.z;
  if (z == 4){                                  // cvt x: 4M floats, 16/thread
    int i = (blockIdx.y * 32 + blockIdx.x) * 256 + threadIdx.x;
    #pragma unroll
    for (int j = 0; j < 4; ++j){
      float4 v = ((const float4*)x)[i + j * 262144];
      ushort4 o;
      o.x = f2bf(v.x); o.y = f2bf(v.y); o.z = f2bf(v.z); o.w = f2bf(v.w);
      ((ushort4*)xb)[i + j * 262144] = o;
    }
    return;
  }
  const float* W = (z==0) ? W0 : (z==1) ? W1 : (z==2) ? W2 : W3;
  u16* out = Wt + (size_t)z * 1048576;
  int k0 = blockIdx.x * 32, n0 = blockIdx.y * 32;
  int tx = threadIdx.x & 31, ty = threadIdx.x >> 5;   // 32 x 8
  #pragma unroll
  for (int i = 0; i < 4; ++i)
    t[ty + i*8][tx] = W[(size_t)(k0 + ty + i*8) * 1024 + n0 + tx];
  __syncthreads();
  #pragma unroll
  for (int i = 0; i < 4; ++i)
    out[(size_t)(n0 + ty + i*8) * 1024 + k0 + tx] = f2bf(t[tx][ty + i*8]);
}

// ---------------- shared GEMM mainloop (2-phase, counted vmcnt) ----------------
// C[128x128] tile at (m0,n0); LDS 2x[128][32] bf16 per operand; XOR swizzle
// on 16B chunks (rule #21). Prefetch stays in flight ACROSS the barrier
// (vmcnt(4), never 0 except tail) — the T4 pattern.
__device__ __forceinline__ void gemm_loop(const u16* __restrict__ Ag,
                                          const u16* __restrict__ Bg,
                                          char (*As)[8192], char (*Bs)[8192],
                                          int m0, int n0, int tid,
                                          f32x4 acc[4][4]){
  const int l  = tid & 63;
  const int lr = l & 15, hg = l >> 4;
  const int w  = tid >> 6;
  const int wr = w >> 1, wc = w & 1;
  // per-thread staging coords (constant across K-tiles)
  const int r0 = tid >> 2,          cc0 = (tid & 3) ^ ((r0 ^ (r0 >> 2)) & 3);
  const int c1 = tid + 256;
  const int r1 = c1 >> 2,           cc1 = (c1 & 3) ^ ((r1 ^ (r1 >> 2)) & 3);

  auto STAGE = [&](int kt, int b){
    const int k0 = kt * 32;
    ASYNC16(Ag + (size_t)(m0 + r0) * 1024 + k0 + cc0*8, As[b] + w*1024);
    ASYNC16(Bg + (size_t)(n0 + r0) * 1024 + k0 + cc0*8, Bs[b] + w*1024);
    ASYNC16(Ag + (size_t)(m0 + r1) * 1024 + k0 + cc1*8, As[b] + 4096 + w*1024);
    ASYNC16(Bg + (size_t)(n0 + r1) * 1024 + k0 + cc1*8, Bs[b] + 4096 + w*1024);
  };
  auto COMPUTE = [&](const char* Asb, const char* Bsb){
    bf16x8 af[4], bf[4];
    #pragma unroll
    for (int mi = 0; mi < 4; ++mi){
      int row = wr*64 + mi*16 + lr;
      af[mi] = *(const bf16x8*)(Asb + row*64 + ((hg ^ ((row ^ (row>>2)) & 3)) << 4));
    }
    #pragma unroll
    for (int ni = 0; ni < 4; ++ni){
      int row = wc*64 + ni*16 + lr;
      bf[ni] = *(const bf16x8*)(Bsb + row*64 + ((hg ^ ((row ^ (row>>2)) & 3)) << 4));
    }
    #pragma unroll
    for (int mi = 0; mi < 4; ++mi)
      #pragma unroll
      for (int ni = 0; ni < 4; ++ni)
        acc[mi][ni] = MFMA_BF16(af[mi], bf[ni], acc[mi][ni]);
  };

  STAGE(0, 0);
  VMCNT0; BARRIER; SCHEDB;               // prologue: buf0 fully ready
  #pragma unroll 1
  for (int kt = 0; kt < 32; kt += 2){
    STAGE(kt + 1, 1);                    // prefetch odd tile -> buf1
    VMCNT4; BARRIER; SCHEDB;             // buf0 retired; prefetch in flight
    COMPUTE(As[0], Bs[0]);
    SCHEDB; BARRIER;                     // all waves done reading buf0
    if (kt + 2 < 32){ STAGE(kt + 2, 0); VMCNT4; } else { VMCNT0; }
    BARRIER; SCHEDB;                     // buf1 retired; prefetch in flight
    COMPUTE(As[1], Bs[1]);
    SCHEDB; BARRIER;                     // all waves done reading buf1
  }
}

// ---------------- QKV projection (XCD-clustered 1D grid, 768 blocks) --------
// Work id w0 = (bid&7)*96 + bid>>3: under round-robin bid->XCD dispatch,
// XCD k runs w0 in [96k, 96k+96) = 3 complete (n0,z) panels -> each 256 KB
// B-panel is pulled into ONE XCD's L2 (not replicated x8), and the 3
// same-m blocks per XCD share A-tiles. L3 traffic ~390 -> ~70 MB (T1).
__global__ __launch_bounds__(256) void gemm_qkv_kernel(const u16* __restrict__ xb,
                                                       const u16* __restrict__ Wt,
                                                       const float* __restrict__ bq,
                                                       const float* __restrict__ bk,
                                                       const float* __restrict__ bv,
                                                       u16* __restrict__ Qb,
                                                       u16* __restrict__ Kb,
                                                       u16* __restrict__ Vt){
  __shared__ alignas(16) char As[2][8192];
  __shared__ alignas(16) char Bs[2][8192];
  const int bid = blockIdx.x;                  // 0..767
  const int w0  = (bid & 7) * 96 + (bid >> 3); // XCD-clustered work id
  const int panel = w0 >> 5;                   // 0..23
  const int z  = panel >> 3;                   // 0..2
  const int n0 = (panel & 7) * 128;
  const int m0 = (w0 & 31) * 128;
  const u16* Bg = Wt + (size_t)z * 1048576;
  const float* bias = (z==0) ? bq : (z==1) ? bk : bv;
  f32x4 acc[4][4];
  #pragma unroll
  for (int i = 0; i < 4; ++i)
    #pragma unroll
    for (int j = 0; j < 4; ++j)
      acc[i][j] = f32x4{0.f, 0.f, 0.f, 0.f};
  gemm_loop(xb, Bg, As, Bs, m0, n0, threadIdx.x, acc);

  const int l = threadIdx.x & 63, w = threadIdx.x >> 6;
  const int lr = l & 15, hg = l >> 4;
  const int wr = w >> 1, wc = w & 1;
  u16* outp = (z == 2) ? Vt : ((z == 1) ? Kb : Qb);
  #pragma unroll
  for (int ni = 0; ni < 4; ++ni){
    int n = n0 + wc*64 + ni*16 + lr;
    float bb = bias[n];
    int h = n >> 6, d = n & 63;
    #pragma unroll
    for (int mi = 0; mi < 4; ++mi){
      int m_base = m0 + wr*64 + mi*16 + hg*4;     // 4 consecutive s
      int b = m_base >> 10, s = m_base & 1023;
      if (z == 2){
        // V^T [b][h][d][s]: the 4 r-values are consecutive in s -> ushort4
        ushort4 o;
        o.x = f2bf(acc[mi][ni][0] + bb);
        o.y = f2bf(acc[mi][ni][1] + bb);
        o.z = f2bf(acc[mi][ni][2] + bb);
        o.w = f2bf(acc[mi][ni][3] + bb);
        *(ushort4*)(outp + ((size_t)((b*16 + h)*64 + d) * 1024 + s)) = o;
      } else {
        #pragma unroll
        for (int r = 0; r < 4; ++r){
          float v = acc[mi][ni][r] + bb;
          outp[(size_t)((b*16 + h)*1024 + s + r) * 64 + d] = f2bf(v);
        }
      }
    }
  }
}

// ---------------- flash attention (causal) ----------------
// grid (8 qt-pairs, 64 bh); 4 waves; block x does q-tiles {x, 15-x}.
// K/V double-buffered; counted-vmcnt pipeline. Ps is per-wave (no barrier).
__global__ __launch_bounds__(256) void attn_kernel(const u16* __restrict__ Qb,
                                                   const u16* __restrict__ Kb,
                                                   const u16* __restrict__ Vt,
                                                   u16* __restrict__ Ao){
  __shared__ alignas(16) char Ksh[2][8192];
  __shared__ alignas(16) char Vsh[2][8192];
  __shared__ alignas(16) char Ps[4 * 16 * 144];
  const int tid = threadIdx.x;
  const int l = tid & 63, w = tid >> 6;
  const int lr = l & 15, hg = l >> 4;
  const int bh = blockIdx.y;
  const u16* Qp = Qb + (size_t)bh * 65536;
  const u16* Kp = Kb + (size_t)bh * 65536;
  const u16* Vp = Vt + (size_t)bh * 65536;
  char* Pw = Ps + w * 2304;

  // stage K/V tile t into buffer b (linear LDS dest, pre-swizzled source)
  auto STAGE = [&](int t, int b){
    int c = tid, row = c >> 3, cc = (c & 7) ^ ((row ^ (row >> 3)) & 7);
    ASYNC16(Kp + (size_t)(t*64 + row)*64 + cc*8, Ksh[b] + w*1024);
    ASYNC16(Vp + (size_t)row*1024 + t*64 + cc*8, Vsh[b] + w*1024);
    c = tid + 256; row = c >> 3; cc = (c & 7) ^ ((row ^ (row >> 3)) & 7);
    ASYNC16(Kp + (size_t)(t*64 + row)*64 + cc*8, Ksh[b] + 4096 + w*1024);
    ASYNC16(Vp + (size_t)row*1024 + t*64 + cc*8, Vsh[b] + 4096 + w*1024);
  };

  #pragma unroll 1
  for (int pass = 0; pass < 2; ++pass){
    const int qt = (pass == 0) ? (int)blockIdx.x : 15 - (int)blockIdx.x;
    const int q0 = qt * 64;

    bf16x8 qf[2];
    {
      const u16* qrow = Qp + (size_t)(q0 + w*16 + lr) * 64 + hg*8;
      qf[0] = *(const bf16x8*)(qrow);
      qf[1] = *(const bf16x8*)(qrow + 32);
    }
    f32x4 acc[4];
    #pragma unroll
    for (int i = 0; i < 4; ++i) acc[i] = f32x4{0.f, 0.f, 0.f, 0.f};
    float mrow[4] = {-INFINITY, -INFINITY, -INFINITY, -INFINITY};
    float lrow[4] = {0.f, 0.f, 0.f, 0.f};

    STAGE(0, 0);
    VMCNT0; BARRIER; SCHEDB;             // prologue: buf0 (and qf) ready

    #pragma unroll 1
    for (int t = 0; t <= qt; ++t){
      const int cur = t & 1;
      if (t < qt){ STAGE(t + 1, cur ^ 1); VMCNT4; }   // prefetch in flight
      else       { VMCNT0; }                          // tail: drain cur
      BARRIER; SCHEDB;                   // cur buffer ready on all waves
      const char* Ks = Ksh[cur];
      const char* Vs = Vsh[cur];

      // S = Q K^T
      float p[4][4];
      #pragma unroll
      for (int ni = 0; ni < 4; ++ni){
        int row = ni*16 + lr;
        int s8 = (row ^ (row >> 3)) & 7;
        bf16x8 k0f = *(const bf16x8*)(Ks + row*128 + ((hg       ^ s8) << 4));
        bf16x8 k1f = *(const bf16x8*)(Ks + row*128 + (((4 + hg) ^ s8) << 4));
        f32x4 zf = f32x4{0.f, 0.f, 0.f, 0.f};
        zf = MFMA_BF16(qf[0], k0f, zf);
        zf = MFMA_BF16(qf[1], k1f, zf);
        #pragma unroll
        for (int r = 0; r < 4; ++r) p[ni][r] = zf[r] * 0.125f;  // D^-0.5
      }
      if (t == qt){                       // diagonal tile: mask tcol > qrow
        #pragma unroll
        for (int ni = 0; ni < 4; ++ni){
          int tcol = ni*16 + lr;
          #pragma unroll
          for (int r = 0; r < 4; ++r){
            int qrow = w*16 + hg*4 + r;
            if (tcol > qrow) p[ni][r] = -INFINITY;
          }
        }
      }
      // online softmax (rows live in 16-lane groups; reg r = q%4)
      float pm[4];
      #pragma unroll
      for (int r = 0; r < 4; ++r)
        pm[r] = fmaxf(fmaxf(p[0][r], p[1][r]), fmaxf(p[2][r], p[3][r]));
      #pragma unroll
      for (int xm = 1; xm < 16; xm <<= 1)
        #pragma unroll
        for (int r = 0; r < 4; ++r)
          pm[r] = fmaxf(pm[r], __shfl_xor(pm[r], xm));
      float corr[4];
      #pragma unroll
      for (int r = 0; r < 4; ++r){
        float mn = fmaxf(mrow[r], pm[r]);
        corr[r] = __expf(mrow[r] - mn);   // -inf start -> 0
        mrow[r] = mn;
      }
      #pragma unroll
      for (int ni = 0; ni < 4; ++ni)
        #pragma unroll
        for (int r = 0; r < 4; ++r)
          p[ni][r] = __expf(p[ni][r] - mrow[r]);
      float psum[4];
      #pragma unroll
      for (int r = 0; r < 4; ++r)
        psum[r] = (p[0][r] + p[1][r]) + (p[2][r] + p[3][r]);
      #pragma unroll
      for (int xm = 1; xm < 16; xm <<= 1)
        #pragma unroll
        for (int r = 0; r < 4; ++r)
          psum[r] += __shfl_xor(psum[r], xm);
      #pragma unroll
      for (int r = 0; r < 4; ++r)
        lrow[r] = lrow[r] * corr[r] + psum[r];
      #pragma unroll
      for (int ni = 0; ni < 4; ++ni)
        #pragma unroll
        for (int r = 0; r < 4; ++r)
          acc[ni][r] *= corr[r];

      // P -> LDS (bf16), C-layout scatter; Ps is PER-WAVE, no barrier
      #pragma unroll
      for (int ni = 0; ni < 4; ++ni)
        #pragma unroll
        for (int r = 0; r < 4; ++r)
          *(u16*)(Pw + (hg*4 + r)*144 + (ni*16 + lr)*2) = f2bf(p[ni][r]);

      // O += P V (compiler inserts lgkmcnt wait for Pw write->read)
      bf16x8 pa[2];
      pa[0] = *(const bf16x8*)(Pw + lr*144 +      hg*16);
      pa[1] = *(const bf16x8*)(Pw + lr*144 + 64 + hg*16);
      #pragma unroll
      for (int ni = 0; ni < 4; ++ni){
        int row = ni*16 + lr;
        int s8 = (row ^ (row >> 3)) & 7;
        bf16x8 v0 = *(const bf16x8*)(Vs + row*128 + ((hg       ^ s8) << 4));
        bf16x8 v1 = *(const bf16x8*)(Vs + row*128 + (((4 + hg) ^ s8) << 4));
        acc[ni] = MFMA_BF16(pa[0], v0, acc[ni]);
        acc[ni] = MFMA_BF16(pa[1], v1, acc[ni]);
      }
      SCHEDB; BARRIER;   // all waves done reading cur before it's restaged
    }

    const int b = bh >> 4, h = bh & 15;
    float invl[4];
    #pragma unroll
    for (int r = 0; r < 4; ++r) invl[r] = 1.f / lrow[r];
    #pragma unroll
    for (int ni = 0; ni < 4; ++ni){
      int d = ni*16 + lr;
      #pragma unroll
      for (int r = 0; r < 4; ++r){
        int q = q0 + w*16 + hg*4 + r;
        Ao[((size_t)(b*1024 + q)) * 1024 + h*64 + d] = f2bf(acc[ni][r] * invl[r]);
      }
    }
  }
}

// ---------------- output projection (fp32 out + bias, XCD-clustered) --------
__global__ __launch_bounds__(256) void gemm_proj_kernel(const u16* __restrict__ Ab,
                                                        const u16* __restrict__ Wot,
                                                        const float* __restrict__ bo,
                                                        float* __restrict__ out){
  __shared__ alignas(16) char As[2][8192];
  __shared__ alignas(16) char Bs[2][8192];
  const int bid = blockIdx.x;                  // 0..255
  const int w0  = (bid & 7) * 32 + (bid >> 3); // XCD k -> panel k (n0)
  const int m0 = (w0 & 31) * 128;
  const int n0 = (w0 >> 5) * 128;
  f32x4 acc[4][4];
  #pragma unroll
  for (int i = 0; i < 4; ++i)
    #pragma unroll
    for (int j = 0; j < 4; ++j)
      acc[i][j] = f32x4{0.f, 0.f, 0.f, 0.f};
  gemm_loop(Ab, Wot, As, Bs, m0, n0, threadIdx.x, acc);

  const int l = threadIdx.x & 63, w = threadIdx.x >> 6;
  const int lr = l & 15, hg = l >> 4;
  const int wr = w >> 1, wc = w & 1;
  #pragma unroll
  for (int ni = 0; ni < 4; ++ni){
    int n = n0 + wc*64 + ni*16 + lr;
    float bb = bo[n];
    #pragma unroll
    for (int mi = 0; mi < 4; ++mi){
      #pragma unroll
      for (int r = 0; r < 4; ++r){
        int m = m0 + wr*64 + mi*16 + hg*4 + r;
        out[(size_t)m * 1024 + n] = acc[mi][ni][r] + bb;
      }
    }
  }
}

extern "C" void kernel_launch(void* const* d_in, const int* in_sizes, int n_in,
                              void* d_out, int out_size, void* d_ws, size_t ws_size,
                              hipStream_t stream){
  (void)in_sizes; (void)n_in; (void)out_size; (void)ws_size;
  const float* x  = (const float*)d_in[0];
  const float* Wq = (const float*)d_in[1];
  const float* bq = (const float*)d_in[2];
  const float* Wk = (const float*)d_in[3];
  const float* bk = (const float*)d_in[4];
  const float* Wv = (const float*)d_in[5];
  const float* bv = (const float*)d_in[6];
  const float* Wo = (const float*)d_in[7];
  const float* bo = (const float*)d_in[8];
  float* out = (float*)d_out;
  char* ws = (char*)d_ws;
  const size_t MB = 1u << 20;
  u16* xb = (u16*)(ws + 0*MB);
  u16* Wt = (u16*)(ws + 8*MB);
  u16* Qb = (u16*)(ws + 16*MB);
  u16* Kb = (u16*)(ws + 24*MB);
  u16* Vt = (u16*)(ws + 32*MB);
  u16* Ao = (u16*)(ws + 40*MB);   // needs 48 MB of ws total

  prep_kernel<<<dim3(32, 32, 5), 256, 0, stream>>>(x, Wq, Wk, Wv, Wo, xb, Wt);
  gemm_qkv_kernel<<<768, 256, 0, stream>>>(xb, Wt, bq, bk, bv, Qb, Kb, Vt);
  attn_kernel<<<dim3(8, 64), 256, 0, stream>>>(Qb, Kb, Vt, Ao);
  gemm_proj_kernel<<<256, 256, 0, stream>>>(Ao, Wt + 3*1048576, bo, out);
}

// Round 15
// 198.057 us; speedup vs baseline: 1.0537x; 1.0537x over previous
//
#include <hip/hip_runtime.h>
#include <hip/hip_bf16.h>

// MultiHeadAttention fused pipeline, bf16 MFMA path.
// B=4 H=16 S=1024 D=64 E=1024, causal, dropout=identity.
// ws layout (48 MB):
//   [0,8M)    xb   : x as bf16            [4096][1024]
//   [8M,16M)  Wt   : W^T bf16, slots q,k,v,o each [1024][1024]
//   [16M,24M) Qb   : [4][16][1024][64] bf16
//   [24M,32M) Kb   : [4][16][1024][64] bf16
//   [32M,40M) Vt   : [4][16][64][1024] bf16  (transposed for PV B-frag)
//   [40M,48M) Ao   : attn out bf16 [4096][1024]

typedef short bf16x8 __attribute__((ext_vector_type(8)));
typedef float f32x4  __attribute__((ext_vector_type(4)));
typedef unsigned short u16;

#define MFMA_BF16(a,b,c) __builtin_amdgcn_mfma_f32_16x16x32_bf16((a),(b),(c),0,0,0)

#define ASYNC16(gp, lp) __builtin_amdgcn_global_load_lds( \
    (const __attribute__((address_space(1))) void*)(gp),  \
    (__attribute__((address_space(3))) void*)(lp), 16, 0, 0)

// Counted-vmcnt pipeline primitives (T4): raw barrier, no vmcnt(0) drain
// in steady state. sched_barrier(0) pins LDS reads after the barrier.
#define VMCNT4  asm volatile("s_waitcnt vmcnt(4)" ::: "memory")
#define VMCNT3  asm volatile("s_waitcnt vmcnt(3)" ::: "memory")
#define VMCNT0  asm volatile("s_waitcnt vmcnt(0)" ::: "memory")
#define BARRIER __builtin_amdgcn_s_barrier()
#define SCHEDB  __builtin_amdgcn_sched_barrier(0)

__device__ __forceinline__ u16 f2bf(float f){
  unsigned int u = __float_as_uint(f);
  u += 0x7FFFu + ((u >> 16) & 1u);   // RNE
  return (u16)(u >> 16);
}

// ---------------- prep: x->bf16 (z=4) + W->W^T bf16 (z=0..3) ----------------
__global__ __launch_bounds__(256) void prep_kernel(const float* __restrict__ x,
                                                   const float* __restrict__ W0,
                                                   const float* __restrict__ W1,
                                                   const float* __restrict__ W2,
                                                   const float* __restrict__ W3,
                                                   u16* __restrict__ xb,
                                                   u16* __restrict__ Wt){
  __shared__ float t[32][33];
  const int z = blockIdx.z;
  if (z == 4){                                  // cvt x: 4M floats, 16/thread
    int i = (blockIdx.y * 32 + blockIdx.x) * 256 + threadIdx.x;
    #pragma unroll
    for (int j = 0; j < 4; ++j){
      float4 v = ((const float4*)x)[i + j * 262144];
      ushort4 o;
      o.x = f2bf(v.x); o.y = f2bf(v.y); o.z = f2bf(v.z); o.w = f2bf(v.w);
      ((ushort4*)xb)[i + j * 262144] = o;
    }
    return;
  }
  const float* W = (z==0) ? W0 : (z==1) ? W1 : (z==2) ? W2 : W3;
  u16* out = Wt + (size_t)z * 1048576;
  int k0 = blockIdx.x * 32, n0 = blockIdx.y * 32;
  int tx = threadIdx.x & 31, ty = threadIdx.x >> 5;   // 32 x 8
  #pragma unroll
  for (int i = 0; i < 4; ++i)
    t[ty + i*8][tx] = W[(size_t)(k0 + ty + i*8) * 1024 + n0 + tx];
  __syncthreads();
  #pragma unroll
  for (int i = 0; i < 4; ++i)
    out[(size_t)(n0 + ty + i*8) * 1024 + k0 + tx] = f2bf(t[tx][ty + i*8]);
}

// ---------------- shared GEMM mainloop (2-phase, counted vmcnt) ----------------
// C[128x128] tile at (m0,n0); LDS 2x[128][32] bf16 per operand; XOR swizzle
// on 16B chunks (rule #21). Prefetch stays in flight ACROSS the barrier
// (vmcnt(4), never 0 except tail) — the T4 pattern.
__device__ __forceinline__ void gemm_loop(const u16* __restrict__ Ag,
                                          const u16* __restrict__ Bg,
                                          char (*As)[8192], char (*Bs)[8192],
                                          int m0, int n0, int tid,
                                          f32x4 acc[4][4]){
  const int l  = tid & 63;
  const int lr = l & 15, hg = l >> 4;
  const int w  = tid >> 6;
  const int wr = w >> 1, wc = w & 1;
  // per-thread staging coords (constant across K-tiles)
  const int r0 = tid >> 2,          cc0 = (tid & 3) ^ ((r0 ^ (r0 >> 2)) & 3);
  const int c1 = tid + 256;
  const int r1 = c1 >> 2,           cc1 = (c1 & 3) ^ ((r1 ^ (r1 >> 2)) & 3);

  auto STAGE = [&](int kt, int b){
    const int k0 = kt * 32;
    ASYNC16(Ag + (size_t)(m0 + r0) * 1024 + k0 + cc0*8, As[b] + w*1024);
    ASYNC16(Bg + (size_t)(n0 + r0) * 1024 + k0 + cc0*8, Bs[b] + w*1024);
    ASYNC16(Ag + (size_t)(m0 + r1) * 1024 + k0 + cc1*8, As[b] + 4096 + w*1024);
    ASYNC16(Bg + (size_t)(n0 + r1) * 1024 + k0 + cc1*8, Bs[b] + 4096 + w*1024);
  };
  auto COMPUTE = [&](const char* Asb, const char* Bsb){
    bf16x8 af[4], bf[4];
    #pragma unroll
    for (int mi = 0; mi < 4; ++mi){
      int row = wr*64 + mi*16 + lr;
      af[mi] = *(const bf16x8*)(Asb + row*64 + ((hg ^ ((row ^ (row>>2)) & 3)) << 4));
    }
    #pragma unroll
    for (int ni = 0; ni < 4; ++ni){
      int row = wc*64 + ni*16 + lr;
      bf[ni] = *(const bf16x8*)(Bsb + row*64 + ((hg ^ ((row ^ (row>>2)) & 3)) << 4));
    }
    #pragma unroll
    for (int mi = 0; mi < 4; ++mi)
      #pragma unroll
      for (int ni = 0; ni < 4; ++ni)
        acc[mi][ni] = MFMA_BF16(af[mi], bf[ni], acc[mi][ni]);
  };

  STAGE(0, 0);
  VMCNT0; BARRIER; SCHEDB;               // prologue: buf0 fully ready
  #pragma unroll 1
  for (int kt = 0; kt < 32; kt += 2){
    STAGE(kt + 1, 1);                    // prefetch odd tile -> buf1
    VMCNT4; BARRIER; SCHEDB;             // buf0 retired; prefetch in flight
    COMPUTE(As[0], Bs[0]);
    SCHEDB; BARRIER;                     // all waves done reading buf0
    if (kt + 2 < 32){ STAGE(kt + 2, 0); VMCNT4; } else { VMCNT0; }
    BARRIER; SCHEDB;                     // buf1 retired; prefetch in flight
    COMPUTE(As[1], Bs[1]);
    SCHEDB; BARRIER;                     // all waves done reading buf1
  }
}

// ---------------- QKV projection (R13 schedule restored) ----------------
__global__ __launch_bounds__(256) void gemm_qkv_kernel(const u16* __restrict__ xb,
                                                       const u16* __restrict__ Wt,
                                                       const float* __restrict__ bq,
                                                       const float* __restrict__ bk,
                                                       const float* __restrict__ bv,
                                                       u16* __restrict__ Qb,
                                                       u16* __restrict__ Kb,
                                                       u16* __restrict__ Vt){
  __shared__ alignas(16) char As[2][8192];
  __shared__ alignas(16) char Bs[2][8192];
  const int z = blockIdx.z;
  const u16* Bg = Wt + (size_t)z * 1048576;
  const float* bias = (z==0) ? bq : (z==1) ? bk : bv;
  const int m0 = blockIdx.x * 128, n0 = blockIdx.y * 128;
  f32x4 acc[4][4];
  #pragma unroll
  for (int i = 0; i < 4; ++i)
    #pragma unroll
    for (int j = 0; j < 4; ++j)
      acc[i][j] = f32x4{0.f, 0.f, 0.f, 0.f};
  gemm_loop(xb, Bg, As, Bs, m0, n0, threadIdx.x, acc);

  const int l = threadIdx.x & 63, w = threadIdx.x >> 6;
  const int lr = l & 15, hg = l >> 4;
  const int wr = w >> 1, wc = w & 1;
  u16* outp = (z == 2) ? Vt : ((z == 1) ? Kb : Qb);
  #pragma unroll
  for (int ni = 0; ni < 4; ++ni){
    int n = n0 + wc*64 + ni*16 + lr;
    float bb = bias[n];
    int h = n >> 6, d = n & 63;
    #pragma unroll
    for (int mi = 0; mi < 4; ++mi){
      int m_base = m0 + wr*64 + mi*16 + hg*4;     // 4 consecutive s
      int b = m_base >> 10, s = m_base & 1023;
      if (z == 2){
        // V^T [b][h][d][s]: the 4 r-values are consecutive in s -> ushort4
        ushort4 o;
        o.x = f2bf(acc[mi][ni][0] + bb);
        o.y = f2bf(acc[mi][ni][1] + bb);
        o.z = f2bf(acc[mi][ni][2] + bb);
        o.w = f2bf(acc[mi][ni][3] + bb);
        *(ushort4*)(outp + ((size_t)((b*16 + h)*64 + d) * 1024 + s)) = o;
      } else {
        #pragma unroll
        for (int r = 0; r < 4; ++r){
          float v = acc[mi][ni][r] + bb;
          outp[(size_t)((b*16 + h)*1024 + s + r) * 64 + d] = f2bf(v);
        }
      }
    }
  }
}

// ---------------- flash attention (causal) ----------------
// grid (8 qt-pairs, 64 bh); 4 waves; block x does q-tiles {x, 15-x}.
// K/V double-buffered; counted-vmcnt pipeline. Ps is per-wave (no barrier).
__global__ __launch_bounds__(256) void attn_kernel(const u16* __restrict__ Qb,
                                                   const u16* __restrict__ Kb,
                                                   const u16* __restrict__ Vt,
                                                   u16* __restrict__ Ao){
  __shared__ alignas(16) char Ksh[2][8192];
  __shared__ alignas(16) char Vsh[2][8192];
  __shared__ alignas(16) char Ps[4 * 16 * 144];
  const int tid = threadIdx.x;
  const int l = tid & 63, w = tid >> 6;
  const int lr = l & 15, hg = l >> 4;
  const int bh = blockIdx.y;
  const u16* Qp = Qb + (size_t)bh * 65536;
  const u16* Kp = Kb + (size_t)bh * 65536;
  const u16* Vp = Vt + (size_t)bh * 65536;
  char* Pw = Ps + w * 2304;

  // stage K/V tile t into buffer b (linear LDS dest, pre-swizzled source)
  auto STAGE = [&](int t, int b){
    int c = tid, row = c >> 3, cc = (c & 7) ^ ((row ^ (row >> 3)) & 7);
    ASYNC16(Kp + (size_t)(t*64 + row)*64 + cc*8, Ksh[b] + w*1024);
    ASYNC16(Vp + (size_t)row*1024 + t*64 + cc*8, Vsh[b] + w*1024);
    c = tid + 256; row = c >> 3; cc = (c & 7) ^ ((row ^ (row >> 3)) & 7);
    ASYNC16(Kp + (size_t)(t*64 + row)*64 + cc*8, Ksh[b] + 4096 + w*1024);
    ASYNC16(Vp + (size_t)row*1024 + t*64 + cc*8, Vsh[b] + 4096 + w*1024);
  };

  #pragma unroll 1
  for (int pass = 0; pass < 2; ++pass){
    const int qt = (pass == 0) ? (int)blockIdx.x : 15 - (int)blockIdx.x;
    const int q0 = qt * 64;

    bf16x8 qf[2];
    {
      const u16* qrow = Qp + (size_t)(q0 + w*16 + lr) * 64 + hg*8;
      qf[0] = *(const bf16x8*)(qrow);
      qf[1] = *(const bf16x8*)(qrow + 32);
    }
    f32x4 acc[4];
    #pragma unroll
    for (int i = 0; i < 4; ++i) acc[i] = f32x4{0.f, 0.f, 0.f, 0.f};
    float mrow[4] = {-INFINITY, -INFINITY, -INFINITY, -INFINITY};
    float lrow[4] = {0.f, 0.f, 0.f, 0.f};

    STAGE(0, 0);
    VMCNT0; BARRIER; SCHEDB;             // prologue: buf0 (and qf) ready

    #pragma unroll 1
    for (int t = 0; t <= qt; ++t){
      const int cur = t & 1;
      if (t < qt){ STAGE(t + 1, cur ^ 1); VMCNT4; }   // prefetch in flight
      else       { VMCNT0; }                          // tail: drain cur
      BARRIER; SCHEDB;                   // cur buffer ready on all waves
      const char* Ks = Ksh[cur];
      const char* Vs = Vsh[cur];

      // S = Q K^T
      float p[4][4];
      #pragma unroll
      for (int ni = 0; ni < 4; ++ni){
        int row = ni*16 + lr;
        int s8 = (row ^ (row >> 3)) & 7;
        bf16x8 k0f = *(const bf16x8*)(Ks + row*128 + ((hg       ^ s8) << 4));
        bf16x8 k1f = *(const bf16x8*)(Ks + row*128 + (((4 + hg) ^ s8) << 4));
        f32x4 zf = f32x4{0.f, 0.f, 0.f, 0.f};
        zf = MFMA_BF16(qf[0], k0f, zf);
        zf = MFMA_BF16(qf[1], k1f, zf);
        #pragma unroll
        for (int r = 0; r < 4; ++r) p[ni][r] = zf[r] * 0.125f;  // D^-0.5
      }
      if (t == qt){                       // diagonal tile: mask tcol > qrow
        #pragma unroll
        for (int ni = 0; ni < 4; ++ni){
          int tcol = ni*16 + lr;
          #pragma unroll
          for (int r = 0; r < 4; ++r){
            int qrow = w*16 + hg*4 + r;
            if (tcol > qrow) p[ni][r] = -INFINITY;
          }
        }
      }
      // online softmax (rows live in 16-lane groups; reg r = q%4)
      float pm[4];
      #pragma unroll
      for (int r = 0; r < 4; ++r)
        pm[r] = fmaxf(fmaxf(p[0][r], p[1][r]), fmaxf(p[2][r], p[3][r]));
      #pragma unroll
      for (int xm = 1; xm < 16; xm <<= 1)
        #pragma unroll
        for (int r = 0; r < 4; ++r)
          pm[r] = fmaxf(pm[r], __shfl_xor(pm[r], xm));
      float corr[4];
      #pragma unroll
      for (int r = 0; r < 4; ++r){
        float mn = fmaxf(mrow[r], pm[r]);
        corr[r] = __expf(mrow[r] - mn);   // -inf start -> 0
        mrow[r] = mn;
      }
      #pragma unroll
      for (int ni = 0; ni < 4; ++ni)
        #pragma unroll
        for (int r = 0; r < 4; ++r)
          p[ni][r] = __expf(p[ni][r] - mrow[r]);
      float psum[4];
      #pragma unroll
      for (int r = 0; r < 4; ++r)
        psum[r] = (p[0][r] + p[1][r]) + (p[2][r] + p[3][r]);
      #pragma unroll
      for (int xm = 1; xm < 16; xm <<= 1)
        #pragma unroll
        for (int r = 0; r < 4; ++r)
          psum[r] += __shfl_xor(psum[r], xm);
      #pragma unroll
      for (int r = 0; r < 4; ++r)
        lrow[r] = lrow[r] * corr[r] + psum[r];
      #pragma unroll
      for (int ni = 0; ni < 4; ++ni)
        #pragma unroll
        for (int r = 0; r < 4; ++r)
          acc[ni][r] *= corr[r];

      // P -> LDS (bf16), C-layout scatter; Ps is PER-WAVE, no barrier
      #pragma unroll
      for (int ni = 0; ni < 4; ++ni)
        #pragma unroll
        for (int r = 0; r < 4; ++r)
          *(u16*)(Pw + (hg*4 + r)*144 + (ni*16 + lr)*2) = f2bf(p[ni][r]);

      // O += P V (compiler inserts lgkmcnt wait for Pw write->read)
      bf16x8 pa[2];
      pa[0] = *(const bf16x8*)(Pw + lr*144 +      hg*16);
      pa[1] = *(const bf16x8*)(Pw + lr*144 + 64 + hg*16);
      #pragma unroll
      for (int ni = 0; ni < 4; ++ni){
        int row = ni*16 + lr;
        int s8 = (row ^ (row >> 3)) & 7;
        bf16x8 v0 = *(const bf16x8*)(Vs + row*128 + ((hg       ^ s8) << 4));
        bf16x8 v1 = *(const bf16x8*)(Vs + row*128 + (((4 + hg) ^ s8) << 4));
        acc[ni] = MFMA_BF16(pa[0], v0, acc[ni]);
        acc[ni] = MFMA_BF16(pa[1], v1, acc[ni]);
      }
      SCHEDB; BARRIER;   // all waves done reading cur before it's restaged
    }

    const int b = bh >> 4, h = bh & 15;
    float invl[4];
    #pragma unroll
    for (int r = 0; r < 4; ++r) invl[r] = 1.f / lrow[r];
    #pragma unroll
    for (int ni = 0; ni < 4; ++ni){
      int d = ni*16 + lr;
      #pragma unroll
      for (int r = 0; r < 4; ++r){
        int q = q0 + w*16 + hg*4 + r;
        Ao[((size_t)(b*1024 + q)) * 1024 + h*64 + d] = f2bf(acc[ni][r] * invl[r]);
      }
    }
  }
}

// ---------------- output projection: 128x64 tiles, 512 blocks (2/CU) --------
// Same 2-phase counted-vmcnt pipeline, 3 loads/stage (A 8KB + B 4KB / buf).
// Wave w owns rows w*32..w*32+31 (acc[2][4] = 32x64 per wave).
__global__ __launch_bounds__(256) void gemm_proj_kernel(const u16* __restrict__ Ab,
                                                        const u16* __restrict__ Wot,
                                                        const float* __restrict__ bo,
                                                        float* __restrict__ out){
  __shared__ alignas(16) char As[2][8192];
  __shared__ alignas(16) char Bs[2][4096];
  const int tid = threadIdx.x;
  const int m0 = blockIdx.x * 128, n0 = blockIdx.y * 64;
  const int l = tid & 63, w = tid >> 6;
  const int lr = l & 15, hg = l >> 4;
  // staging coords: A rows 0-63 (r0) and 64-127 (r1); B rows 0-63 (r0)
  const int r0 = tid >> 2,  cc0 = (tid & 3) ^ ((r0 ^ (r0 >> 2)) & 3);
  const int c1 = tid + 256;
  const int r1 = c1 >> 2,   cc1 = (c1 & 3) ^ ((r1 ^ (r1 >> 2)) & 3);

  auto STAGE = [&](int kt, int b){
    const int k0 = kt * 32;
    ASYNC16(Ab  + (size_t)(m0 + r0) * 1024 + k0 + cc0*8, As[b] + w*1024);
    ASYNC16(Ab  + (size_t)(m0 + r1) * 1024 + k0 + cc1*8, As[b] + 4096 + w*1024);
    ASYNC16(Wot + (size_t)(n0 + r0) * 1024 + k0 + cc0*8, Bs[b] + w*1024);
  };
  f32x4 acc[2][4];
  #pragma unroll
  for (int i = 0; i < 2; ++i)
    #pragma unroll
    for (int j = 0; j < 4; ++j)
      acc[i][j] = f32x4{0.f, 0.f, 0.f, 0.f};
  auto COMPUTE = [&](const char* Asb, const char* Bsb){
    bf16x8 af[2], bf[4];
    #pragma unroll
    for (int mi = 0; mi < 2; ++mi){
      int row = w*32 + mi*16 + lr;
      af[mi] = *(const bf16x8*)(Asb + row*64 + ((hg ^ ((row ^ (row>>2)) & 3)) << 4));
    }
    #pragma unroll
    for (int ni = 0; ni < 4; ++ni){
      int row = ni*16 + lr;
      bf[ni] = *(const bf16x8*)(Bsb + row*64 + ((hg ^ ((row ^ (row>>2)) & 3)) << 4));
    }
    #pragma unroll
    for (int mi = 0; mi < 2; ++mi)
      #pragma unroll
      for (int ni = 0; ni < 4; ++ni)
        acc[mi][ni] = MFMA_BF16(af[mi], bf[ni], acc[mi][ni]);
  };

  STAGE(0, 0);
  VMCNT0; BARRIER; SCHEDB;
  #pragma unroll 1
  for (int kt = 0; kt < 32; kt += 2){
    STAGE(kt + 1, 1);
    VMCNT3; BARRIER; SCHEDB;             // buf0's 3 (older) retired
    COMPUTE(As[0], Bs[0]);
    SCHEDB; BARRIER;                     // all waves done reading buf0
    if (kt + 2 < 32){ STAGE(kt + 2, 0); VMCNT3; } else { VMCNT0; }
    BARRIER; SCHEDB;
    COMPUTE(As[1], Bs[1]);
    SCHEDB; BARRIER;
  }

  #pragma unroll
  for (int ni = 0; ni < 4; ++ni){
    int n = n0 + ni*16 + lr;
    float bb = bo[n];
    #pragma unroll
    for (int mi = 0; mi < 2; ++mi){
      #pragma unroll
      for (int r = 0; r < 4; ++r){
        int m = m0 + w*32 + mi*16 + hg*4 + r;
        out[(size_t)m * 1024 + n] = acc[mi][ni][r] + bb;
      }
    }
  }
}

extern "C" void kernel_launch(void* const* d_in, const int* in_sizes, int n_in,
                              void* d_out, int out_size, void* d_ws, size_t ws_size,
                              hipStream_t stream){
  (void)in_sizes; (void)n_in; (void)out_size; (void)ws_size;
  const float* x  = (const float*)d_in[0];
  const float* Wq = (const float*)d_in[1];
  const float* bq = (const float*)d_in[2];
  const float* Wk = (const float*)d_in[3];
  const float* bk = (const float*)d_in[4];
  const float* Wv = (const float*)d_in[5];
  const float* bv = (const float*)d_in[6];
  const float* Wo = (const float*)d_in[7];
  const float* bo = (const float*)d_in[8];
  float* out = (float*)d_out;
  char* ws = (char*)d_ws;
  const size_t MB = 1u << 20;
  u16* xb = (u16*)(ws + 0*MB);
  u16* Wt = (u16*)(ws + 8*MB);
  u16* Qb = (u16*)(ws + 16*MB);
  u16* Kb = (u16*)(ws + 24*MB);
  u16* Vt = (u16*)(ws + 32*MB);
  u16* Ao = (u16*)(ws + 40*MB);   // needs 48 MB of ws total

  prep_kernel<<<dim3(32, 32, 5), 256, 0, stream>>>(x, Wq, Wk, Wv, Wo, xb, Wt);
  gemm_qkv_kernel<<<dim3(32, 8, 3), 256, 0, stream>>>(xb, Wt, bq, bk, bv, Qb, Kb, Vt);
  attn_kernel<<<dim3(8, 64), 256, 0, stream>>>(Qb, Kb, Vt, Ao);
  gemm_proj_kernel<<<dim3(32, 16), 256, 0, stream>>>(Ao, Wt + 3*1048576, bo, out);
}